// Round 8
// baseline (511.779 us; speedup 1.0000x reference)
//
#include <hip/hip_runtime.h>
#include <hip/hip_bf16.h>
#include <stdint.h>

#define H_ 12
#define D_ 32
#define N_ 49
#define C_ 384
#define B_TOT 2048
#define BH 24576            // B_TOT * H_
#define M_ROWS 100352       // B_TOT * N_
#define SCALE 0.17677669529663689f

typedef float f32x4 __attribute__((ext_vector_type(4)));
typedef __bf16 bf16x8 __attribute__((ext_vector_type(8)));
typedef unsigned short ushortx8 __attribute__((ext_vector_type(8)));

static __device__ __forceinline__ unsigned short f2bf(float f) {
  __bf16 b = (__bf16)f;
  return __builtin_bit_cast(unsigned short, b);
}

static __device__ __forceinline__ uint4 pack8(float4 a, float4 b) {
  ushortx8 v;
  v[0] = f2bf(a.x); v[1] = f2bf(a.y); v[2] = f2bf(a.z); v[3] = f2bf(a.w);
  v[4] = f2bf(b.x); v[5] = f2bf(b.y); v[6] = f2bf(b.z); v[7] = f2bf(b.w);
  return __builtin_bit_cast(uint4, v);
}

// async global->LDS, 16B per lane; LDS dest must be linear in lane order
#define GL16(gp, lp)                                                        \
  __builtin_amdgcn_global_load_lds(                                         \
      (const __attribute__((address_space(1))) unsigned int*)(gp),          \
      (__attribute__((address_space(3))) unsigned int*)(lp), 16, 0, 0)

// ---------------------------------------------------------------------------
// K0: prep: cast wq/wp to bf16 + build comb table (x no longer cast)
// ---------------------------------------------------------------------------
__global__ void prep(const float* __restrict__ wq, const float* __restrict__ wpw,
                     const float* __restrict__ mask, const float* __restrict__ rpb,
                     const int* __restrict__ ridx,
                     unsigned short* __restrict__ wq_bf,
                     unsigned short* __restrict__ wp_bf,
                     float* __restrict__ comb) {
  const int blk = blockIdx.x, tid = threadIdx.x;
  if (blk < 216) {
    const int i = blk * 256 + tid;  // 55296 chunks exact
    float4 a = ((const float4*)wq)[2 * i];
    float4 b = ((const float4*)wq)[2 * i + 1];
    *(uint4*)&wq_bf[(size_t)i * 8] = pack8(a, b);
  } else if (blk < 288) {
    const int i = (blk - 216) * 256 + tid;  // 18432 chunks exact
    float4 a = ((const float4*)wpw)[2 * i];
    float4 b = ((const float4*)wpw)[2 * i + 1];
    *(uint4*)&wp_bf[(size_t)i * 8] = pack8(a, b);
  } else {
    const int wh = blk - 288;            // 0..767 = w*12+h
    const int w = wh / 12, h = wh - w * 12;
    float* cb = comb + (size_t)wh * 4096;
    const float* mw = mask + (size_t)w * N_ * N_;
    for (int e = tid; e < 4096; e += 256) {
      const int r = e >> 6, c = e & 63;
      float v;
      if (c >= N_) v = -1e30f;
      else if (r >= N_) v = 0.0f;
      else v = mw[r * N_ + c] + rpb[ridx[r * N_ + c] * H_ + h];
      cb[e] = v;
    }
  }
}

// ---------------------------------------------------------------------------
// K1: QKV GEMM: qkv = x @ qkv_w.T + qkv_b, x read as fp32 directly.
// A: reg-staged fp32 -> cvt bf16 at ds_write (issue-early/write-late).
// B: global_load_lds bf16. XCD-group swizzle. Coalesced LDS-restaged epilogue.
// ---------------------------------------------------------------------------
__global__ __launch_bounds__(256, 3)
void qkv_gemm(const float* __restrict__ A,
              const unsigned short* __restrict__ W,
              const float* __restrict__ bias, unsigned short* __restrict__ qkv) {
  __shared__ __align__(16) unsigned short smem[16384];  // 2 bufs x (A 4096 + B 4096 shorts)
  const int tid = threadIdx.x;
  const int w = blockIdx.x;
  const int t = (w & 7) * 882 + (w >> 3);   // 7056 = 8 XCD x 882; 882 = 98x9
  const int bm = t / 9, bn = t - bm * 9;
  const int lane = tid & 63, wv = tid >> 6;
  const int wm = wv >> 1, wn = wv & 1;
  const int lo = lane & 15, hi = lane >> 4;

  // A staging: thread handles row=tid>>1, 16 fp32 cols at (tid&1)*16
  const int arow = tid >> 1, acg = tid & 1;
  const int ac0 = (acg * 2) ^ ((arow >> 1) & 3);      // swizzled chunk slots
  const int ac1 = (acg * 2 + 1) ^ ((arow >> 1) & 3);
  // B staging (gload_lds): 512 chunks, 2/thread, pre-swizzled source
  const int sr0 = tid >> 2, sq0 = (tid & 3) ^ ((sr0 >> 1) & 3);
  const int ci1 = tid + 256;
  const int sr1 = ci1 >> 2, sq1 = (ci1 & 3) ^ ((sr1 >> 1) & 3);

  const float* Ab = A + (size_t)bm * 128 * 384 + arow * 384 + acg * 16;
  const unsigned short* Wb = W + (size_t)bn * 128 * 384;

  f32x4 acc[4][4];
#pragma unroll
  for (int i = 0; i < 4; i++)
#pragma unroll
    for (int j = 0; j < 4; j++)
#pragma unroll
      for (int r = 0; r < 4; r++) acc[i][j][r] = 0.0f;

  // prologue: stage kt=0 into buf0
  {
    float4 s0 = *(const float4*)(Ab + 0);
    float4 s1 = *(const float4*)(Ab + 4);
    float4 s2 = *(const float4*)(Ab + 8);
    float4 s3 = *(const float4*)(Ab + 12);
    GL16(Wb + sr0 * 384 + sq0 * 8, smem + 4096 + tid * 8);
    GL16(Wb + sr1 * 384 + sq1 * 8, smem + 4096 + ci1 * 8);
    *(uint4*)&smem[(arow * 4 + ac0) * 8] = pack8(s0, s1);
    *(uint4*)&smem[(arow * 4 + ac1) * 8] = pack8(s2, s3);
  }
  __syncthreads();

  int buf = 0;
  for (int kt = 0; kt < 12; kt++) {
    float4 s0, s1, s2, s3;
    if (kt < 11) {
      const int kk = (kt + 1) * 32;
      s0 = *(const float4*)(Ab + kk + 0);
      s1 = *(const float4*)(Ab + kk + 4);
      s2 = *(const float4*)(Ab + kk + 8);
      s3 = *(const float4*)(Ab + kk + 12);
      unsigned short* nb = smem + (buf ^ 1) * 8192;
      GL16(Wb + sr0 * 384 + kk + sq0 * 8, nb + 4096 + tid * 8);
      GL16(Wb + sr1 * 384 + kk + sq1 * 8, nb + 4096 + ci1 * 8);
    }
    const unsigned short* ba = smem + buf * 8192;
    bf16x8 af[4], bfm[4];
#pragma unroll
    for (int mt = 0; mt < 4; mt++) {
      const int row = wm * 64 + mt * 16 + lo;
      af[mt] = *(const bf16x8*)&ba[(row * 4 + (hi ^ ((row >> 1) & 3))) * 8];
    }
#pragma unroll
    for (int nt = 0; nt < 4; nt++) {
      const int row = wn * 64 + nt * 16 + lo;
      bfm[nt] = *(const bf16x8*)&ba[4096 + (row * 4 + (hi ^ ((row >> 1) & 3))) * 8];
    }
#pragma unroll
    for (int mt = 0; mt < 4; mt++)
#pragma unroll
      for (int nt = 0; nt < 4; nt++)
        acc[mt][nt] = __builtin_amdgcn_mfma_f32_16x16x32_bf16(af[mt], bfm[nt], acc[mt][nt], 0, 0, 0);
    if (kt < 11) {
      unsigned short* nb = smem + (buf ^ 1) * 8192;
      *(uint4*)&nb[(arow * 4 + ac0) * 8] = pack8(s0, s1);
      *(uint4*)&nb[(arow * 4 + ac1) * 8] = pack8(s2, s3);
    }
    __syncthreads();
    buf ^= 1;
  }

  // epilogue: per-wave 64x64 bf16 subtile in LDS (4K shorts/wave, c16-XOR swz),
  // then full 64B-line stores to qkv[which][b][h][sq][d].
  unsigned short* ep = smem + wv * 4096;
#pragma unroll
  for (int nt = 0; nt < 4; nt++) {
    const int j = bn * 128 + wn * 64 + nt * 16 + lo;
    const float bj = bias[j];
    const float mul = (j < 384) ? SCALE : 1.0f;
    const int c16 = nt * 2 + (lo >> 3);
    const int wi = lo & 7;
#pragma unroll
    for (int mt = 0; mt < 4; mt++) {
#pragma unroll
      for (int r = 0; r < 4; r++) {
        const int row = mt * 16 + hi * 4 + r;
        ep[row * 64 + ((c16 ^ hi) << 3) + wi] = f2bf((acc[mt][nt][r] + bj) * mul);
      }
    }
  }
#pragma unroll
  for (int cc = 0; cc < 2; cc++) {
    const int cidx = cc * 64 + lane;
    const int lr = cidx >> 1, lch = cidx & 1;
    const int i = bm * 128 + wm * 64 + lr;
    const int b = i / 49, sq = i - b * 49;
    const int j0 = bn * 128 + wn * 64 + lch * 32;
    const int which = j0 / 384;
    const int rem = j0 - which * 384;
    const int h = rem >> 5;
    const int hlr = (lr >> 2) & 3;
    unsigned short* dst = qkv + ((size_t)which * BH + (size_t)b * H_ + h) * (N_ * D_) + sq * D_;
#pragma unroll
    for (int q = 0; q < 4; q++) {
      const int c16r = lch * 4 + q;
      *(uint4*)(dst + q * 8) = *(const uint4*)&ep[lr * 64 + ((c16r ^ hlr) << 3)];
    }
  }
}

// ---------------------------------------------------------------------------
// K2: attention per (b,h). 1 wave. Stride-64 XOR-swizzled P/VT (12.3 KB LDS
// -> 13 blocks/CU). Otherwise R3/R7 structure verbatim.
// ---------------------------------------------------------------------------
__global__ __launch_bounds__(64, 2)
void attn_kernel(const unsigned short* __restrict__ qkv,
                 const float* __restrict__ comb,
                 float* __restrict__ probs,
                 unsigned short* __restrict__ av) {
  __shared__ __align__(16) unsigned short P[64 * 64];
  __shared__ __align__(16) unsigned short VT[32 * 64];
  const int lane = threadIdx.x;
  const int lo = lane & 15, hi = lane >> 4;
  const int l7 = lo & 7;
  const int h = blockIdx.x, b = blockIdx.y;

  const unsigned short* qp = qkv + (size_t)(b * H_ + h) * (N_ * D_);
  const unsigned short* kp = qp + (size_t)BH * (N_ * D_);
  const unsigned short* vp = kp + (size_t)BH * (N_ * D_);

  {
    unsigned int* vz = (unsigned int*)VT;
#pragma unroll
    for (int i = 0; i < 16; i++) vz[lane + 64 * i] = 0u;
  }
  __syncthreads();

  bf16x8 aq[4], bk[4];
#pragma unroll
  for (int t = 0; t < 4; t++) {
    aq[t] = *(const bf16x8*)(qp + (t * 16 + lo) * D_ + hi * 8);
    bk[t] = *(const bf16x8*)(kp + (t * 16 + lo) * D_ + hi * 8);
  }
  f32x4 s[4][4];
#pragma unroll
  for (int mt = 0; mt < 4; mt++)
#pragma unroll
    for (int nt = 0; nt < 4; nt++) {
#pragma unroll
      for (int r = 0; r < 4; r++) s[mt][nt][r] = 0.0f;
      s[mt][nt] = __builtin_amdgcn_mfma_f32_16x16x32_bf16(aq[mt], bk[nt], s[mt][nt], 0, 0, 0);
    }

  // stage V transposed into VT[d][sq], chunk-XOR swizzled
#pragma unroll
  for (int it = 0; it < 4; it++) {
    const int idx = it * 64 + lane;
    if (idx < 196) {
      const int sq = idx >> 2, ch = idx & 3;
      ushortx8 vv = *(const ushortx8*)(vp + sq * D_ + ch * 8);
#pragma unroll
      for (int jj = 0; jj < 8; jj++)
        VT[(ch * 8 + jj) * 64 + (((sq >> 3) ^ jj) << 3) + (sq & 7)] = vv[jj];
    }
  }

  const float* cb = comb + (size_t)((b & 63) * H_ + h) * 4096;
#pragma unroll
  for (int mt = 0; mt < 4; mt++) {
#pragma unroll
    for (int r = 0; r < 4; r++) {
      const int row = mt * 16 + hi * 4 + r;
      const float* crow = cb + row * 64 + lo;
      float v0 = s[mt][0][r] + crow[0];
      float v1 = s[mt][1][r] + crow[16];
      float v2 = s[mt][2][r] + crow[32];
      float v3 = s[mt][3][r] + crow[48];
      float m = fmaxf(fmaxf(v0, v1), fmaxf(v2, v3));
      m = fmaxf(m, __shfl_xor(m, 1));
      m = fmaxf(m, __shfl_xor(m, 2));
      m = fmaxf(m, __shfl_xor(m, 4));
      m = fmaxf(m, __shfl_xor(m, 8));
      v0 = __expf(v0 - m); v1 = __expf(v1 - m);
      v2 = __expf(v2 - m); v3 = __expf(v3 - m);
      float sum = v0 + v1 + v2 + v3;
      sum += __shfl_xor(sum, 1);
      sum += __shfl_xor(sum, 2);
      sum += __shfl_xor(sum, 4);
      sum += __shfl_xor(sum, 8);
      const float rinv = 1.0f / sum;
      s[mt][0][r] = v0 * rinv; s[mt][1][r] = v1 * rinv;
      s[mt][2][r] = v2 * rinv; s[mt][3][r] = v3 * rinv;
    }
  }

  const size_t pbase = (size_t)(b * H_ + h) * N_ * N_;
#pragma unroll
  for (int mt = 0; mt < 4; mt++) {
#pragma unroll
    for (int r = 0; r < 4; r++) {
      const int row = mt * 16 + hi * 4 + r;
      if (row < N_) {
#pragma unroll
        for (int nt = 0; nt < 4; nt++) {
          const int c = nt * 16 + lo;
          if (c < N_) probs[pbase + row * N_ + c] = s[mt][nt][r];
        }
      }
      const int r7 = row & 7;
#pragma unroll
      for (int nt = 0; nt < 4; nt++)
        P[row * 64 + (((nt * 2 + (lo >> 3)) ^ r7) << 3) + l7] = f2bf(s[mt][nt][r]);
    }
  }
  __syncthreads();

  f32x4 o[4][2];
#pragma unroll
  for (int mt = 0; mt < 4; mt++)
#pragma unroll
    for (int n2 = 0; n2 < 2; n2++)
#pragma unroll
      for (int r = 0; r < 4; r++) o[mt][n2][r] = 0.0f;
#pragma unroll
  for (int ks = 0; ks < 2; ks++) {
    bf16x8 pa[4], vb[2];
#pragma unroll
    for (int mt = 0; mt < 4; mt++)
      pa[mt] = *(const bf16x8*)&P[(mt * 16 + lo) * 64 + (((ks * 4 + hi) ^ l7) << 3)];
#pragma unroll
    for (int n2 = 0; n2 < 2; n2++)
      vb[n2] = *(const bf16x8*)&VT[(n2 * 16 + lo) * 64 + (((ks * 4 + hi) ^ l7) << 3)];
#pragma unroll
    for (int mt = 0; mt < 4; mt++)
#pragma unroll
      for (int n2 = 0; n2 < 2; n2++)
        o[mt][n2] = __builtin_amdgcn_mfma_f32_16x16x32_bf16(pa[mt], vb[n2], o[mt][n2], 0, 0, 0);
  }

  __syncthreads();
#pragma unroll
  for (int mt = 0; mt < 4; mt++) {
#pragma unroll
    for (int r = 0; r < 4; r++) {
      const int row = mt * 16 + hi * 4 + r;
      if (row < N_) {
#pragma unroll
        for (int n2 = 0; n2 < 2; n2++)
          P[row * 40 + n2 * 16 + lo] = f2bf(o[mt][n2][r]);
      }
    }
  }
  if (lane < N_) {
    unsigned short* dst = av + ((size_t)b * N_ + lane) * C_ + h * D_;
    const unsigned short* src = P + lane * 40;
#pragma unroll
    for (int q = 0; q < 4; q++)
      *(uint4*)(dst + q * 8) = *(const uint4*)(src + q * 8);
  }
}

// ---------------------------------------------------------------------------
// K3: proj GEMM: out = av @ proj_w.T + proj_b. gload_lds both sides (bf16).
// XCD-group swizzle (groups of 3 N-tiles). (R7 version, verbatim)
// ---------------------------------------------------------------------------
__global__ __launch_bounds__(256, 4)
void proj_gemm(const unsigned short* __restrict__ A,
               const unsigned short* __restrict__ W,
               const float* __restrict__ bias, float* __restrict__ out) {
  __shared__ __align__(16) unsigned short smem[16384];  // 32 KB
  const int tid = threadIdx.x;
  const int w = blockIdx.x;
  const int t = (w & 7) * 294 + (w >> 3);   // 2352 = 8 x 294; 294 = 98x3
  const int bm = t / 3, bn = t - bm * 3;
  const int lane = tid & 63, wv = tid >> 6;
  const int wm = wv >> 1, wn = wv & 1;
  const int lo = lane & 15, hi = lane >> 4;

  const int sr0 = tid >> 2, sq0 = (tid & 3) ^ ((sr0 >> 1) & 3);
  const int ci1 = tid + 256;
  const int sr1 = ci1 >> 2, sq1 = (ci1 & 3) ^ ((sr1 >> 1) & 3);

  const unsigned short* Ab = A + (size_t)bm * 128 * 384;
  const unsigned short* Wb = W + (size_t)bn * 128 * 384;

  f32x4 acc[4][4];
#pragma unroll
  for (int i = 0; i < 4; i++)
#pragma unroll
    for (int j = 0; j < 4; j++)
#pragma unroll
      for (int r = 0; r < 4; r++) acc[i][j][r] = 0.0f;

  {
    unsigned short* b0 = smem;
    GL16(Ab + sr0 * 384 + sq0 * 8, b0 + tid * 8);
    GL16(Ab + sr1 * 384 + sq1 * 8, b0 + ci1 * 8);
    GL16(Wb + sr0 * 384 + sq0 * 8, b0 + 4096 + tid * 8);
    GL16(Wb + sr1 * 384 + sq1 * 8, b0 + 4096 + ci1 * 8);
  }
  __syncthreads();

  int buf = 0;
  for (int kt = 0; kt < 12; kt++) {
    if (kt < 11) {
      const int kk = (kt + 1) * 32;
      unsigned short* nb = smem + (buf ^ 1) * 8192;
      GL16(Ab + sr0 * 384 + kk + sq0 * 8, nb + tid * 8);
      GL16(Ab + sr1 * 384 + kk + sq1 * 8, nb + ci1 * 8);
      GL16(Wb + sr0 * 384 + kk + sq0 * 8, nb + 4096 + tid * 8);
      GL16(Wb + sr1 * 384 + kk + sq1 * 8, nb + 4096 + ci1 * 8);
    }
    const unsigned short* ba = smem + buf * 8192;
    bf16x8 af[4], bfm[4];
#pragma unroll
    for (int mt = 0; mt < 4; mt++) {
      const int row = wm * 64 + mt * 16 + lo;
      af[mt] = *(const bf16x8*)&ba[(row * 4 + (hi ^ ((row >> 1) & 3))) * 8];
    }
#pragma unroll
    for (int nt = 0; nt < 4; nt++) {
      const int row = wn * 64 + nt * 16 + lo;
      bfm[nt] = *(const bf16x8*)&ba[4096 + (row * 4 + (hi ^ ((row >> 1) & 3))) * 8];
    }
#pragma unroll
    for (int mt = 0; mt < 4; mt++)
#pragma unroll
      for (int nt = 0; nt < 4; nt++)
        acc[mt][nt] = __builtin_amdgcn_mfma_f32_16x16x32_bf16(af[mt], bfm[nt], acc[mt][nt], 0, 0, 0);
    __syncthreads();
    buf ^= 1;
  }

#pragma unroll
  for (int nt = 0; nt < 4; nt++) {
    const int j = bn * 128 + wn * 64 + nt * 16 + lo;
    const float bj = bias[j];
#pragma unroll
    for (int mt = 0; mt < 4; mt++) {
#pragma unroll
      for (int r = 0; r < 4; r++) {
        const int i = bm * 128 + wm * 64 + mt * 16 + hi * 4 + r;
        out[(size_t)i * 384 + j] = acc[mt][nt][r] + bj;
      }
    }
  }
}

// ---------------------------------------------------------------------------
extern "C" void kernel_launch(void* const* d_in, const int* in_sizes, int n_in,
                              void* d_out, int out_size, void* d_ws, size_t ws_size,
                              hipStream_t stream) {
  const float* x      = (const float*)d_in[0];
  const float* mask   = (const float*)d_in[1];
  const float* qkv_w  = (const float*)d_in[2];
  const float* qkv_b  = (const float*)d_in[3];
  const float* proj_w = (const float*)d_in[4];
  const float* proj_b = (const float*)d_in[5];
  const float* rpb    = (const float*)d_in[6];
  const int*   ridx   = (const int*)d_in[7];

  // ws: qkv 231.2 MB | av 77.1 MB | comb 12.6 MB | weights
  unsigned short* qkv   = (unsigned short*)d_ws;
  unsigned short* av    = qkv + (size_t)3 * BH * N_ * D_;
  float* comb           = (float*)(av + (size_t)M_ROWS * C_);
  unsigned short* wq_bf = (unsigned short*)(comb + 768 * 4096);
  unsigned short* wp_bf = wq_bf + 1152 * 384;
  float* out   = (float*)d_out;
  float* probs = out + (size_t)M_ROWS * C_;

  prep<<<1056, 256, 0, stream>>>(qkv_w, proj_w, mask, rpb, ridx,
                                 wq_bf, wp_bf, comb);
  qkv_gemm<<<7056, 256, 0, stream>>>(x, wq_bf, qkv_b, qkv);
  attn_kernel<<<dim3(H_, B_TOT), 64, 0, stream>>>(qkv, comb, probs, av);
  proj_gemm<<<2352, 256, 0, stream>>>(av, wp_bf, proj_b, out);
}

// Round 9
// 466.468 us; speedup vs baseline: 1.0971x; 1.0971x over previous
//
#include <hip/hip_runtime.h>
#include <hip/hip_bf16.h>
#include <stdint.h>

#define H_ 12
#define D_ 32
#define N_ 49
#define C_ 384
#define B_TOT 2048
#define BH 24576            // B_TOT * H_
#define M_ROWS 100352       // B_TOT * N_
#define SCALE 0.17677669529663689f

typedef float f32x4 __attribute__((ext_vector_type(4)));
typedef __bf16 bf16x8 __attribute__((ext_vector_type(8)));
typedef unsigned short ushortx8 __attribute__((ext_vector_type(8)));

static __device__ __forceinline__ unsigned short f2bf(float f) {
  __bf16 b = (__bf16)f;
  return __builtin_bit_cast(unsigned short, b);
}

static __device__ __forceinline__ uint4 pack8(float4 a, float4 b) {
  ushortx8 v;
  v[0] = f2bf(a.x); v[1] = f2bf(a.y); v[2] = f2bf(a.z); v[3] = f2bf(a.w);
  v[4] = f2bf(b.x); v[5] = f2bf(b.y); v[6] = f2bf(b.z); v[7] = f2bf(b.w);
  return __builtin_bit_cast(uint4, v);
}

// async global->LDS, 16B per lane; LDS dest must be linear in lane order
#define GL16(gp, lp)                                                        \
  __builtin_amdgcn_global_load_lds(                                         \
      (const __attribute__((address_space(1))) unsigned int*)(gp),          \
      (__attribute__((address_space(3))) unsigned int*)(lp), 16, 0, 0)

// ---------------------------------------------------------------------------
// K0: fused prep: cast x/wq/wp to bf16 + build comb table (R7 version)
// ---------------------------------------------------------------------------
__global__ void prep(const float* __restrict__ x, const float* __restrict__ wq,
                     const float* __restrict__ wpw, const float* __restrict__ mask,
                     const float* __restrict__ rpb, const int* __restrict__ ridx,
                     unsigned short* __restrict__ x_bf,
                     unsigned short* __restrict__ wq_bf,
                     unsigned short* __restrict__ wp_bf,
                     float* __restrict__ comb) {
  const int blk = blockIdx.x, tid = threadIdx.x;
  if (blk < 2048) {
    for (int i = blk * 256 + tid; i < 4816896; i += 2048 * 256) {
      float4 a = ((const float4*)x)[2 * i];
      float4 b = ((const float4*)x)[2 * i + 1];
      *(uint4*)&x_bf[(size_t)i * 8] = pack8(a, b);
    }
  } else if (blk < 2264) {
    const int i = (blk - 2048) * 256 + tid;  // 55296 chunks exact
    float4 a = ((const float4*)wq)[2 * i];
    float4 b = ((const float4*)wq)[2 * i + 1];
    *(uint4*)&wq_bf[(size_t)i * 8] = pack8(a, b);
  } else if (blk < 2336) {
    const int i = (blk - 2264) * 256 + tid;  // 18432 chunks exact
    float4 a = ((const float4*)wpw)[2 * i];
    float4 b = ((const float4*)wpw)[2 * i + 1];
    *(uint4*)&wp_bf[(size_t)i * 8] = pack8(a, b);
  } else {
    const int wh = blk - 2336;           // 0..767 = w*12+h
    const int w = wh / 12, h = wh - w * 12;
    float* cb = comb + (size_t)wh * 4096;
    const float* mw = mask + (size_t)w * N_ * N_;
    for (int e = tid; e < 4096; e += 256) {
      const int r = e >> 6, c = e & 63;
      float v;
      if (c >= N_) v = -1e30f;
      else if (r >= N_) v = 0.0f;
      else v = mw[r * N_ + c] + rpb[ridx[r * N_ + c] * H_ + h];
      cb[e] = v;
    }
  }
}

// ---------------------------------------------------------------------------
// K1: QKV GEMM (bf16): qkv = x_bf @ qkv_w.T + qkv_b. 256x128 tile, 8 waves
// (4m x 2n). global_load_lds staging both sides, XOR-swizzled LDS.
// XCD-group swizzle (3528 = 8 x 441, 441 = 49 groups x 9 ntiles).
// Coalesced epilogue via per-wave 8KB LDS restage.
// ---------------------------------------------------------------------------
__global__ __launch_bounds__(512, 4)
void qkv_gemm(const unsigned short* __restrict__ A,
              const unsigned short* __restrict__ W,
              const float* __restrict__ bias, unsigned short* __restrict__ qkv) {
  __shared__ __align__(16) unsigned short smem[32768];  // 64 KB
  const int tid = threadIdx.x;
  const int w = blockIdx.x;
  const int t = (w & 7) * 441 + (w >> 3);
  const int bm = t / 9, bn = t - bm * 9;
  const int lane = tid & 63, wv = tid >> 6;   // 8 waves
  const int wm = wv >> 1, wn = wv & 1;        // 4m x 2n
  const int lo = lane & 15, hi = lane >> 4;

  // A: 1024 chunks (256 rows x 4), 2/thread. B: 512 chunks (128 rows x 4), 1/thread.
  // LDS slot ci holds global chunk (row=ci>>2, (ci&3)^((row>>1)&3)).
  const int ar0 = tid >> 2,  aq0 = (tid & 3) ^ ((ar0 >> 1) & 3);
  const int aci1 = tid + 512;
  const int ar1 = aci1 >> 2, aq1 = (aci1 & 3) ^ ((ar1 >> 1) & 3);

  const unsigned short* Ab = A + (size_t)bm * 256 * 384;
  const unsigned short* Wb = W + (size_t)bn * 128 * 384;

  f32x4 acc[4][4];
#pragma unroll
  for (int i = 0; i < 4; i++)
#pragma unroll
    for (int j = 0; j < 4; j++)
#pragma unroll
      for (int r = 0; r < 4; r++) acc[i][j][r] = 0.0f;

  // prologue: stage kt=0 into buf0 (A at 0, B at 8192 shorts)
  {
    unsigned short* b0 = smem;
    GL16(Ab + ar0 * 384 + aq0 * 8, b0 + tid * 8);
    GL16(Ab + ar1 * 384 + aq1 * 8, b0 + aci1 * 8);
    GL16(Wb + ar0 * 384 + aq0 * 8, b0 + 8192 + tid * 8);
  }
  __syncthreads();

  int buf = 0;
  for (int kt = 0; kt < 12; kt++) {
    if (kt < 11) {
      const int kk = (kt + 1) * 32;
      unsigned short* nb = smem + (buf ^ 1) * 12288;
      GL16(Ab + ar0 * 384 + kk + aq0 * 8, nb + tid * 8);
      GL16(Ab + ar1 * 384 + kk + aq1 * 8, nb + aci1 * 8);
      GL16(Wb + ar0 * 384 + kk + aq0 * 8, nb + 8192 + tid * 8);
    }
    const unsigned short* ba = smem + buf * 12288;
    bf16x8 af[4], bfm[4];
#pragma unroll
    for (int mt = 0; mt < 4; mt++) {
      const int row = wm * 64 + mt * 16 + lo;
      af[mt] = *(const bf16x8*)&ba[(row * 4 + (hi ^ ((row >> 1) & 3))) * 8];
    }
#pragma unroll
    for (int nt = 0; nt < 4; nt++) {
      const int row = wn * 64 + nt * 16 + lo;
      bfm[nt] = *(const bf16x8*)&ba[8192 + (row * 4 + (hi ^ ((row >> 1) & 3))) * 8];
    }
#pragma unroll
    for (int mt = 0; mt < 4; mt++)
#pragma unroll
      for (int nt = 0; nt < 4; nt++)
        acc[mt][nt] = __builtin_amdgcn_mfma_f32_16x16x32_bf16(af[mt], bfm[nt], acc[mt][nt], 0, 0, 0);
    __syncthreads();
    buf ^= 1;
  }

  // epilogue: per-wave 64x64 bf16 subtile in LDS (4K shorts/wave, c16-XOR swz),
  // then full 64B-line stores to qkv[which][b][h][sq][d].
  unsigned short* ep = smem + wv * 4096;
#pragma unroll
  for (int nt = 0; nt < 4; nt++) {
    const int j = bn * 128 + wn * 64 + nt * 16 + lo;
    const float bj = bias[j];
    const float mul = (j < 384) ? SCALE : 1.0f;
    const int c16 = nt * 2 + (lo >> 3);
    const int wi = lo & 7;
#pragma unroll
    for (int mt = 0; mt < 4; mt++) {
#pragma unroll
      for (int r = 0; r < 4; r++) {
        const int row = mt * 16 + hi * 4 + r;
        ep[row * 64 + ((c16 ^ hi) << 3) + wi] = f2bf((acc[mt][nt][r] + bj) * mul);
      }
    }
  }
#pragma unroll
  for (int cc = 0; cc < 2; cc++) {
    const int cidx = cc * 64 + lane;
    const int lr = cidx >> 1, lch = cidx & 1;
    const int i = bm * 256 + wm * 64 + lr;
    const int b = i / 49, sq = i - b * 49;
    const int j0 = bn * 128 + wn * 64 + lch * 32;
    const int which = j0 / 384;
    const int rem = j0 - which * 384;
    const int h = rem >> 5;
    const int hlr = (lr >> 2) & 3;
    unsigned short* dst = qkv + ((size_t)which * BH + (size_t)b * H_ + h) * (N_ * D_) + sq * D_;
#pragma unroll
    for (int q = 0; q < 4; q++) {
      const int c16r = lch * 4 + q;
      *(uint4*)(dst + q * 8) = *(const uint4*)&ep[lr * 64 + ((c16r ^ hlr) << 3)];
    }
  }
}

// ---------------------------------------------------------------------------
// K2: attention per (b,h). 1 wave. Stride-64 XOR-swizzled P/VT, 12 KB LDS.
// (R8 version — correctness-proven, perf-neutral vs R7.)
// ---------------------------------------------------------------------------
__global__ __launch_bounds__(64, 2)
void attn_kernel(const unsigned short* __restrict__ qkv,
                 const float* __restrict__ comb,
                 float* __restrict__ probs,
                 unsigned short* __restrict__ av) {
  __shared__ __align__(16) unsigned short P[64 * 64];
  __shared__ __align__(16) unsigned short VT[32 * 64];
  const int lane = threadIdx.x;
  const int lo = lane & 15, hi = lane >> 4;
  const int l7 = lo & 7;
  const int h = blockIdx.x, b = blockIdx.y;

  const unsigned short* qp = qkv + (size_t)(b * H_ + h) * (N_ * D_);
  const unsigned short* kp = qp + (size_t)BH * (N_ * D_);
  const unsigned short* vp = kp + (size_t)BH * (N_ * D_);

  {
    unsigned int* vz = (unsigned int*)VT;
#pragma unroll
    for (int i = 0; i < 16; i++) vz[lane + 64 * i] = 0u;
  }
  __syncthreads();

  bf16x8 aq[4], bk[4];
#pragma unroll
  for (int t = 0; t < 4; t++) {
    aq[t] = *(const bf16x8*)(qp + (t * 16 + lo) * D_ + hi * 8);
    bk[t] = *(const bf16x8*)(kp + (t * 16 + lo) * D_ + hi * 8);
  }
  f32x4 s[4][4];
#pragma unroll
  for (int mt = 0; mt < 4; mt++)
#pragma unroll
    for (int nt = 0; nt < 4; nt++) {
#pragma unroll
      for (int r = 0; r < 4; r++) s[mt][nt][r] = 0.0f;
      s[mt][nt] = __builtin_amdgcn_mfma_f32_16x16x32_bf16(aq[mt], bk[nt], s[mt][nt], 0, 0, 0);
    }

  // stage V transposed into VT[d][sq], chunk-XOR swizzled
#pragma unroll
  for (int it = 0; it < 4; it++) {
    const int idx = it * 64 + lane;
    if (idx < 196) {
      const int sq = idx >> 2, ch = idx & 3;
      ushortx8 vv = *(const ushortx8*)(vp + sq * D_ + ch * 8);
#pragma unroll
      for (int jj = 0; jj < 8; jj++)
        VT[(ch * 8 + jj) * 64 + (((sq >> 3) ^ jj) << 3) + (sq & 7)] = vv[jj];
    }
  }

  const float* cb = comb + (size_t)((b & 63) * H_ + h) * 4096;
#pragma unroll
  for (int mt = 0; mt < 4; mt++) {
#pragma unroll
    for (int r = 0; r < 4; r++) {
      const int row = mt * 16 + hi * 4 + r;
      const float* crow = cb + row * 64 + lo;
      float v0 = s[mt][0][r] + crow[0];
      float v1 = s[mt][1][r] + crow[16];
      float v2 = s[mt][2][r] + crow[32];
      float v3 = s[mt][3][r] + crow[48];
      float m = fmaxf(fmaxf(v0, v1), fmaxf(v2, v3));
      m = fmaxf(m, __shfl_xor(m, 1));
      m = fmaxf(m, __shfl_xor(m, 2));
      m = fmaxf(m, __shfl_xor(m, 4));
      m = fmaxf(m, __shfl_xor(m, 8));
      v0 = __expf(v0 - m); v1 = __expf(v1 - m);
      v2 = __expf(v2 - m); v3 = __expf(v3 - m);
      float sum = v0 + v1 + v2 + v3;
      sum += __shfl_xor(sum, 1);
      sum += __shfl_xor(sum, 2);
      sum += __shfl_xor(sum, 4);
      sum += __shfl_xor(sum, 8);
      const float rinv = 1.0f / sum;
      s[mt][0][r] = v0 * rinv; s[mt][1][r] = v1 * rinv;
      s[mt][2][r] = v2 * rinv; s[mt][3][r] = v3 * rinv;
    }
  }

  const size_t pbase = (size_t)(b * H_ + h) * N_ * N_;
#pragma unroll
  for (int mt = 0; mt < 4; mt++) {
#pragma unroll
    for (int r = 0; r < 4; r++) {
      const int row = mt * 16 + hi * 4 + r;
      if (row < N_) {
#pragma unroll
        for (int nt = 0; nt < 4; nt++) {
          const int c = nt * 16 + lo;
          if (c < N_) probs[pbase + row * N_ + c] = s[mt][nt][r];
        }
      }
      const int r7 = row & 7;
#pragma unroll
      for (int nt = 0; nt < 4; nt++)
        P[row * 64 + (((nt * 2 + (lo >> 3)) ^ r7) << 3) + l7] = f2bf(s[mt][nt][r]);
    }
  }
  __syncthreads();

  f32x4 o[4][2];
#pragma unroll
  for (int mt = 0; mt < 4; mt++)
#pragma unroll
    for (int n2 = 0; n2 < 2; n2++)
#pragma unroll
      for (int r = 0; r < 4; r++) o[mt][n2][r] = 0.0f;
#pragma unroll
  for (int ks = 0; ks < 2; ks++) {
    bf16x8 pa[4], vb[2];
#pragma unroll
    for (int mt = 0; mt < 4; mt++)
      pa[mt] = *(const bf16x8*)&P[(mt * 16 + lo) * 64 + (((ks * 4 + hi) ^ l7) << 3)];
#pragma unroll
    for (int n2 = 0; n2 < 2; n2++)
      vb[n2] = *(const bf16x8*)&VT[(n2 * 16 + lo) * 64 + (((ks * 4 + hi) ^ l7) << 3)];
#pragma unroll
    for (int mt = 0; mt < 4; mt++)
#pragma unroll
      for (int n2 = 0; n2 < 2; n2++)
        o[mt][n2] = __builtin_amdgcn_mfma_f32_16x16x32_bf16(pa[mt], vb[n2], o[mt][n2], 0, 0, 0);
  }

  __syncthreads();
#pragma unroll
  for (int mt = 0; mt < 4; mt++) {
#pragma unroll
    for (int r = 0; r < 4; r++) {
      const int row = mt * 16 + hi * 4 + r;
      if (row < N_) {
#pragma unroll
        for (int n2 = 0; n2 < 2; n2++)
          P[row * 40 + n2 * 16 + lo] = f2bf(o[mt][n2][r]);
      }
    }
  }
  if (lane < N_) {
    unsigned short* dst = av + ((size_t)b * N_ + lane) * C_ + h * D_;
    const unsigned short* src = P + lane * 40;
#pragma unroll
    for (int q = 0; q < 4; q++)
      *(uint4*)(dst + q * 8) = *(const uint4*)(src + q * 8);
  }
}

// ---------------------------------------------------------------------------
// K3: proj GEMM: out = av @ proj_w.T + proj_b. gload_lds both sides (bf16).
// XCD-group swizzle (groups of 3 N-tiles). (R7 version, verbatim)
// ---------------------------------------------------------------------------
__global__ __launch_bounds__(256, 4)
void proj_gemm(const unsigned short* __restrict__ A,
               const unsigned short* __restrict__ W,
               const float* __restrict__ bias, float* __restrict__ out) {
  __shared__ __align__(16) unsigned short smem[16384];  // 32 KB
  const int tid = threadIdx.x;
  const int w = blockIdx.x;
  const int t = (w & 7) * 294 + (w >> 3);   // 2352 = 8 x 294; 294 = 98x3
  const int bm = t / 3, bn = t - bm * 3;
  const int lane = tid & 63, wv = tid >> 6;
  const int wm = wv >> 1, wn = wv & 1;
  const int lo = lane & 15, hi = lane >> 4;

  const int sr0 = tid >> 2, sq0 = (tid & 3) ^ ((sr0 >> 1) & 3);
  const int ci1 = tid + 256;
  const int sr1 = ci1 >> 2, sq1 = (ci1 & 3) ^ ((sr1 >> 1) & 3);

  const unsigned short* Ab = A + (size_t)bm * 128 * 384;
  const unsigned short* Wb = W + (size_t)bn * 128 * 384;

  f32x4 acc[4][4];
#pragma unroll
  for (int i = 0; i < 4; i++)
#pragma unroll
    for (int j = 0; j < 4; j++)
#pragma unroll
      for (int r = 0; r < 4; r++) acc[i][j][r] = 0.0f;

  {
    unsigned short* b0 = smem;
    GL16(Ab + sr0 * 384 + sq0 * 8, b0 + tid * 8);
    GL16(Ab + sr1 * 384 + sq1 * 8, b0 + ci1 * 8);
    GL16(Wb + sr0 * 384 + sq0 * 8, b0 + 4096 + tid * 8);
    GL16(Wb + sr1 * 384 + sq1 * 8, b0 + 4096 + ci1 * 8);
  }
  __syncthreads();

  int buf = 0;
  for (int kt = 0; kt < 12; kt++) {
    if (kt < 11) {
      const int kk = (kt + 1) * 32;
      unsigned short* nb = smem + (buf ^ 1) * 8192;
      GL16(Ab + sr0 * 384 + kk + sq0 * 8, nb + tid * 8);
      GL16(Ab + sr1 * 384 + kk + sq1 * 8, nb + ci1 * 8);
      GL16(Wb + sr0 * 384 + kk + sq0 * 8, nb + 4096 + tid * 8);
      GL16(Wb + sr1 * 384 + kk + sq1 * 8, nb + 4096 + ci1 * 8);
    }
    const unsigned short* ba = smem + buf * 8192;
    bf16x8 af[4], bfm[4];
#pragma unroll
    for (int mt = 0; mt < 4; mt++) {
      const int row = wm * 64 + mt * 16 + lo;
      af[mt] = *(const bf16x8*)&ba[(row * 4 + (hi ^ ((row >> 1) & 3))) * 8];
    }
#pragma unroll
    for (int nt = 0; nt < 4; nt++) {
      const int row = wn * 64 + nt * 16 + lo;
      bfm[nt] = *(const bf16x8*)&ba[4096 + (row * 4 + (hi ^ ((row >> 1) & 3))) * 8];
    }
#pragma unroll
    for (int mt = 0; mt < 4; mt++)
#pragma unroll
      for (int nt = 0; nt < 4; nt++)
        acc[mt][nt] = __builtin_amdgcn_mfma_f32_16x16x32_bf16(af[mt], bfm[nt], acc[mt][nt], 0, 0, 0);
    __syncthreads();
    buf ^= 1;
  }

#pragma unroll
  for (int nt = 0; nt < 4; nt++) {
    const int j = bn * 128 + wn * 64 + nt * 16 + lo;
    const float bj = bias[j];
#pragma unroll
    for (int mt = 0; mt < 4; mt++) {
#pragma unroll
      for (int r = 0; r < 4; r++) {
        const int i = bm * 128 + wm * 64 + mt * 16 + hi * 4 + r;
        out[(size_t)i * 384 + j] = acc[mt][nt][r] + bj;
      }
    }
  }
}

// ---------------------------------------------------------------------------
extern "C" void kernel_launch(void* const* d_in, const int* in_sizes, int n_in,
                              void* d_out, int out_size, void* d_ws, size_t ws_size,
                              hipStream_t stream) {
  const float* x      = (const float*)d_in[0];
  const float* mask   = (const float*)d_in[1];
  const float* qkv_w  = (const float*)d_in[2];
  const float* qkv_b  = (const float*)d_in[3];
  const float* proj_w = (const float*)d_in[4];
  const float* proj_b = (const float*)d_in[5];
  const float* rpb    = (const float*)d_in[6];
  const int*   ridx   = (const int*)d_in[7];

  // ws: qkv 231.2 MB | x_bf/av (aliased) 77.1 MB | comb 12.6 MB | weights
  unsigned short* qkv   = (unsigned short*)d_ws;
  unsigned short* x_bf  = qkv + (size_t)3 * BH * N_ * D_;   // alias: av
  unsigned short* av    = x_bf;
  float* comb           = (float*)(x_bf + (size_t)M_ROWS * C_);
  unsigned short* wq_bf = (unsigned short*)(comb + 768 * 4096);
  unsigned short* wp_bf = wq_bf + 1152 * 384;
  float* out   = (float*)d_out;
  float* probs = out + (size_t)M_ROWS * C_;

  prep<<<3104, 256, 0, stream>>>(x, qkv_w, proj_w, mask, rpb, ridx,
                                 x_bf, wq_bf, wp_bf, comb);
  qkv_gemm<<<3528, 512, 0, stream>>>(x_bf, wq_bf, qkv_b, qkv);
  attn_kernel<<<dim3(H_, B_TOT), 64, 0, stream>>>(qkv, comb, probs, av);
  proj_gemm<<<2352, 256, 0, stream>>>(av, wp_bf, proj_b, out);
}

// Round 10
// 457.739 us; speedup vs baseline: 1.1181x; 1.0191x over previous
//
#include <hip/hip_runtime.h>
#include <hip/hip_bf16.h>
#include <stdint.h>

#define H_ 12
#define D_ 32
#define N_ 49
#define C_ 384
#define B_TOT 2048
#define BH 24576            // B_TOT * H_
#define M_ROWS 100352       // B_TOT * N_
#define SCALE 0.17677669529663689f

typedef float f32x4 __attribute__((ext_vector_type(4)));
typedef __bf16 bf16x8 __attribute__((ext_vector_type(8)));
typedef unsigned short ushortx8 __attribute__((ext_vector_type(8)));

static __device__ __forceinline__ unsigned short f2bf(float f) {
  __bf16 b = (__bf16)f;
  return __builtin_bit_cast(unsigned short, b);
}

static __device__ __forceinline__ uint4 pack8(float4 a, float4 b) {
  ushortx8 v;
  v[0] = f2bf(a.x); v[1] = f2bf(a.y); v[2] = f2bf(a.z); v[3] = f2bf(a.w);
  v[4] = f2bf(b.x); v[5] = f2bf(b.y); v[6] = f2bf(b.z); v[7] = f2bf(b.w);
  return __builtin_bit_cast(uint4, v);
}

// async global->LDS, 16B per lane; LDS dest must be linear in lane order
#define GL16(gp, lp)                                                        \
  __builtin_amdgcn_global_load_lds(                                         \
      (const __attribute__((address_space(1))) unsigned int*)(gp),          \
      (__attribute__((address_space(3))) unsigned int*)(lp), 16, 0, 0)

// ---------------------------------------------------------------------------
// K0: fused prep: cast x/wq/wp to bf16 + build comb table.
// comb stored SWIZZLED: comb4[wh][row][lane16][4] so attn reads one float4
// per row holding cols {lane, lane+16, lane+32, lane+48}.
// ---------------------------------------------------------------------------
__global__ void prep(const float* __restrict__ x, const float* __restrict__ wq,
                     const float* __restrict__ wpw, const float* __restrict__ mask,
                     const float* __restrict__ rpb, const int* __restrict__ ridx,
                     unsigned short* __restrict__ x_bf,
                     unsigned short* __restrict__ wq_bf,
                     unsigned short* __restrict__ wp_bf,
                     float* __restrict__ comb) {
  const int blk = blockIdx.x, tid = threadIdx.x;
  if (blk < 2048) {
    for (int i = blk * 256 + tid; i < 4816896; i += 2048 * 256) {
      float4 a = ((const float4*)x)[2 * i];
      float4 b = ((const float4*)x)[2 * i + 1];
      *(uint4*)&x_bf[(size_t)i * 8] = pack8(a, b);
    }
  } else if (blk < 2264) {
    const int i = (blk - 2048) * 256 + tid;  // 55296 chunks exact
    float4 a = ((const float4*)wq)[2 * i];
    float4 b = ((const float4*)wq)[2 * i + 1];
    *(uint4*)&wq_bf[(size_t)i * 8] = pack8(a, b);
  } else if (blk < 2336) {
    const int i = (blk - 2264) * 256 + tid;  // 18432 chunks exact
    float4 a = ((const float4*)wpw)[2 * i];
    float4 b = ((const float4*)wpw)[2 * i + 1];
    *(uint4*)&wp_bf[(size_t)i * 8] = pack8(a, b);
  } else {
    const int wh = blk - 2336;           // 0..767 = w*12+h
    const int w = wh / 12, h = wh - w * 12;
    float* cb = comb + (size_t)wh * 4096;
    const float* mw = mask + (size_t)w * N_ * N_;
    for (int e = tid; e < 4096; e += 256) {
      const int r = e >> 6, c = e & 63;
      float v;
      if (c >= N_) v = -1e30f;
      else if (r >= N_) v = 0.0f;
      else v = mw[r * N_ + c] + rpb[ridx[r * N_ + c] * H_ + h];
      cb[(r * 16 + (c & 15)) * 4 + (c >> 4)] = v;   // swizzled slot
    }
  }
}

// ---------------------------------------------------------------------------
// K1: QKV GEMM (bf16): qkv = x_bf @ qkv_w.T + qkv_b. 128x128 tile, 4 waves.
// global_load_lds staging, XOR-swizzled LDS. XCD-group swizzle.
// Coalesced epilogue via per-wave LDS restage. (R7 version, verbatim)
// ---------------------------------------------------------------------------
__global__ __launch_bounds__(256, 4)
void qkv_gemm(const unsigned short* __restrict__ A,
              const unsigned short* __restrict__ W,
              const float* __restrict__ bias, unsigned short* __restrict__ qkv) {
  __shared__ __align__(16) unsigned short smem[16384];  // 32 KB
  const int tid = threadIdx.x;
  const int w = blockIdx.x;
  const int t = (w & 7) * 882 + (w >> 3);   // 7056 = 8 XCD x 882; 882 = 98x9
  const int bm = t / 9, bn = t - bm * 9;
  const int lane = tid & 63, wv = tid >> 6;
  const int wm = wv >> 1, wn = wv & 1;
  const int lo = lane & 15, hi = lane >> 4;

  const int sr0 = tid >> 2, sq0 = (tid & 3) ^ ((sr0 >> 1) & 3);
  const int ci1 = tid + 256;
  const int sr1 = ci1 >> 2, sq1 = (ci1 & 3) ^ ((sr1 >> 1) & 3);

  const unsigned short* Ab = A + (size_t)bm * 128 * 384;
  const unsigned short* Wb = W + (size_t)bn * 128 * 384;

  f32x4 acc[4][4];
#pragma unroll
  for (int i = 0; i < 4; i++)
#pragma unroll
    for (int j = 0; j < 4; j++)
#pragma unroll
      for (int r = 0; r < 4; r++) acc[i][j][r] = 0.0f;

  {
    unsigned short* b0 = smem;
    GL16(Ab + sr0 * 384 + sq0 * 8, b0 + tid * 8);
    GL16(Ab + sr1 * 384 + sq1 * 8, b0 + ci1 * 8);
    GL16(Wb + sr0 * 384 + sq0 * 8, b0 + 4096 + tid * 8);
    GL16(Wb + sr1 * 384 + sq1 * 8, b0 + 4096 + ci1 * 8);
  }
  __syncthreads();

  int buf = 0;
  for (int kt = 0; kt < 12; kt++) {
    if (kt < 11) {
      const int kk = (kt + 1) * 32;
      unsigned short* nb = smem + (buf ^ 1) * 8192;
      GL16(Ab + sr0 * 384 + kk + sq0 * 8, nb + tid * 8);
      GL16(Ab + sr1 * 384 + kk + sq1 * 8, nb + ci1 * 8);
      GL16(Wb + sr0 * 384 + kk + sq0 * 8, nb + 4096 + tid * 8);
      GL16(Wb + sr1 * 384 + kk + sq1 * 8, nb + 4096 + ci1 * 8);
    }
    const unsigned short* ba = smem + buf * 8192;
    bf16x8 af[4], bfm[4];
#pragma unroll
    for (int mt = 0; mt < 4; mt++) {
      const int row = wm * 64 + mt * 16 + lo;
      af[mt] = *(const bf16x8*)&ba[(row * 4 + (hi ^ ((row >> 1) & 3))) * 8];
    }
#pragma unroll
    for (int nt = 0; nt < 4; nt++) {
      const int row = wn * 64 + nt * 16 + lo;
      bfm[nt] = *(const bf16x8*)&ba[4096 + (row * 4 + (hi ^ ((row >> 1) & 3))) * 8];
    }
#pragma unroll
    for (int mt = 0; mt < 4; mt++)
#pragma unroll
      for (int nt = 0; nt < 4; nt++)
        acc[mt][nt] = __builtin_amdgcn_mfma_f32_16x16x32_bf16(af[mt], bfm[nt], acc[mt][nt], 0, 0, 0);
    __syncthreads();
    buf ^= 1;
  }

  unsigned short* ep = smem + wv * 4096;
#pragma unroll
  for (int nt = 0; nt < 4; nt++) {
    const int j = bn * 128 + wn * 64 + nt * 16 + lo;
    const float bj = bias[j];
    const float mul = (j < 384) ? SCALE : 1.0f;
    const int c16 = nt * 2 + (lo >> 3);
    const int wi = lo & 7;
#pragma unroll
    for (int mt = 0; mt < 4; mt++) {
#pragma unroll
      for (int r = 0; r < 4; r++) {
        const int row = mt * 16 + hi * 4 + r;
        ep[row * 64 + ((c16 ^ hi) << 3) + wi] = f2bf((acc[mt][nt][r] + bj) * mul);
      }
    }
  }
#pragma unroll
  for (int cc = 0; cc < 2; cc++) {
    const int cidx = cc * 64 + lane;
    const int lr = cidx >> 1, lch = cidx & 1;
    const int i = bm * 128 + wm * 64 + lr;
    const int b = i / 49, sq = i - b * 49;
    const int j0 = bn * 128 + wn * 64 + lch * 32;
    const int which = j0 / 384;
    const int rem = j0 - which * 384;
    const int h = rem >> 5;
    const int hlr = (lr >> 2) & 3;
    unsigned short* dst = qkv + ((size_t)which * BH + (size_t)b * H_ + h) * (N_ * D_) + sq * D_;
#pragma unroll
    for (int q = 0; q < 4; q++) {
      const int c16r = lch * 4 + q;
      *(uint4*)(dst + q * 8) = *(const uint4*)&ep[lr * 64 + ((c16r ^ hlr) << 3)];
    }
  }
}

// ---------------------------------------------------------------------------
// K2: attention per (b,h). 1 wave. Stride-64 XOR-swizzled P/VT, 12 KB LDS.
// comb read as ONE float4 per row (pre-swizzled layout from prep).
// ---------------------------------------------------------------------------
__global__ __launch_bounds__(64, 2)
void attn_kernel(const unsigned short* __restrict__ qkv,
                 const float* __restrict__ comb,
                 float* __restrict__ probs,
                 unsigned short* __restrict__ av) {
  __shared__ __align__(16) unsigned short P[64 * 64];
  __shared__ __align__(16) unsigned short VT[32 * 64];
  const int lane = threadIdx.x;
  const int lo = lane & 15, hi = lane >> 4;
  const int l7 = lo & 7;
  const int h = blockIdx.x, b = blockIdx.y;

  const unsigned short* qp = qkv + (size_t)(b * H_ + h) * (N_ * D_);
  const unsigned short* kp = qp + (size_t)BH * (N_ * D_);
  const unsigned short* vp = kp + (size_t)BH * (N_ * D_);

  {
    unsigned int* vz = (unsigned int*)VT;
#pragma unroll
    for (int i = 0; i < 16; i++) vz[lane + 64 * i] = 0u;
  }
  __syncthreads();

  bf16x8 aq[4], bk[4];
#pragma unroll
  for (int t = 0; t < 4; t++) {
    aq[t] = *(const bf16x8*)(qp + (t * 16 + lo) * D_ + hi * 8);
    bk[t] = *(const bf16x8*)(kp + (t * 16 + lo) * D_ + hi * 8);
  }
  f32x4 s[4][4];
#pragma unroll
  for (int mt = 0; mt < 4; mt++)
#pragma unroll
    for (int nt = 0; nt < 4; nt++) {
#pragma unroll
      for (int r = 0; r < 4; r++) s[mt][nt][r] = 0.0f;
      s[mt][nt] = __builtin_amdgcn_mfma_f32_16x16x32_bf16(aq[mt], bk[nt], s[mt][nt], 0, 0, 0);
    }

  // stage V transposed into VT[d][sq], chunk-XOR swizzled
#pragma unroll
  for (int it = 0; it < 4; it++) {
    const int idx = it * 64 + lane;
    if (idx < 196) {
      const int sq = idx >> 2, ch = idx & 3;
      ushortx8 vv = *(const ushortx8*)(vp + sq * D_ + ch * 8);
#pragma unroll
      for (int jj = 0; jj < 8; jj++)
        VT[(ch * 8 + jj) * 64 + (((sq >> 3) ^ jj) << 3) + (sq & 7)] = vv[jj];
    }
  }

  const float* cb = comb + (size_t)((b & 63) * H_ + h) * 4096;
#pragma unroll
  for (int mt = 0; mt < 4; mt++) {
#pragma unroll
    for (int r = 0; r < 4; r++) {
      const int row = mt * 16 + hi * 4 + r;
      const float4 cr = *(const float4*)(cb + (row * 16 + lo) * 4);
      float v0 = s[mt][0][r] + cr.x;
      float v1 = s[mt][1][r] + cr.y;
      float v2 = s[mt][2][r] + cr.z;
      float v3 = s[mt][3][r] + cr.w;
      float m = fmaxf(fmaxf(v0, v1), fmaxf(v2, v3));
      m = fmaxf(m, __shfl_xor(m, 1));
      m = fmaxf(m, __shfl_xor(m, 2));
      m = fmaxf(m, __shfl_xor(m, 4));
      m = fmaxf(m, __shfl_xor(m, 8));
      v0 = __expf(v0 - m); v1 = __expf(v1 - m);
      v2 = __expf(v2 - m); v3 = __expf(v3 - m);
      float sum = v0 + v1 + v2 + v3;
      sum += __shfl_xor(sum, 1);
      sum += __shfl_xor(sum, 2);
      sum += __shfl_xor(sum, 4);
      sum += __shfl_xor(sum, 8);
      const float rinv = 1.0f / sum;
      s[mt][0][r] = v0 * rinv; s[mt][1][r] = v1 * rinv;
      s[mt][2][r] = v2 * rinv; s[mt][3][r] = v3 * rinv;
    }
  }

  const size_t pbase = (size_t)(b * H_ + h) * N_ * N_;
#pragma unroll
  for (int mt = 0; mt < 4; mt++) {
#pragma unroll
    for (int r = 0; r < 4; r++) {
      const int row = mt * 16 + hi * 4 + r;
      if (row < N_) {
#pragma unroll
        for (int nt = 0; nt < 4; nt++) {
          const int c = nt * 16 + lo;
          if (c < N_) probs[pbase + row * N_ + c] = s[mt][nt][r];
        }
      }
      const int r7 = row & 7;
#pragma unroll
      for (int nt = 0; nt < 4; nt++)
        P[row * 64 + (((nt * 2 + (lo >> 3)) ^ r7) << 3) + l7] = f2bf(s[mt][nt][r]);
    }
  }
  __syncthreads();

  f32x4 o[4][2];
#pragma unroll
  for (int mt = 0; mt < 4; mt++)
#pragma unroll
    for (int n2 = 0; n2 < 2; n2++)
#pragma unroll
      for (int r = 0; r < 4; r++) o[mt][n2][r] = 0.0f;
#pragma unroll
  for (int ks = 0; ks < 2; ks++) {
    bf16x8 pa[4], vb[2];
#pragma unroll
    for (int mt = 0; mt < 4; mt++)
      pa[mt] = *(const bf16x8*)&P[(mt * 16 + lo) * 64 + (((ks * 4 + hi) ^ l7) << 3)];
#pragma unroll
    for (int n2 = 0; n2 < 2; n2++)
      vb[n2] = *(const bf16x8*)&VT[(n2 * 16 + lo) * 64 + (((ks * 4 + hi) ^ l7) << 3)];
#pragma unroll
    for (int mt = 0; mt < 4; mt++)
#pragma unroll
      for (int n2 = 0; n2 < 2; n2++)
        o[mt][n2] = __builtin_amdgcn_mfma_f32_16x16x32_bf16(pa[mt], vb[n2], o[mt][n2], 0, 0, 0);
  }

  __syncthreads();
#pragma unroll
  for (int mt = 0; mt < 4; mt++) {
#pragma unroll
    for (int r = 0; r < 4; r++) {
      const int row = mt * 16 + hi * 4 + r;
      if (row < N_) {
#pragma unroll
        for (int n2 = 0; n2 < 2; n2++)
          P[row * 40 + n2 * 16 + lo] = f2bf(o[mt][n2][r]);
      }
    }
  }
  if (lane < N_) {
    unsigned short* dst = av + ((size_t)b * N_ + lane) * C_ + h * D_;
    const unsigned short* src = P + lane * 40;
#pragma unroll
    for (int q = 0; q < 4; q++)
      *(uint4*)(dst + q * 8) = *(const uint4*)(src + q * 8);
  }
}

// ---------------------------------------------------------------------------
// K3: proj GEMM: out = av @ proj_w.T + proj_b. gload_lds both sides (bf16).
// XCD-group swizzle (groups of 3 N-tiles). (R7 version, verbatim)
// ---------------------------------------------------------------------------
__global__ __launch_bounds__(256, 4)
void proj_gemm(const unsigned short* __restrict__ A,
               const unsigned short* __restrict__ W,
               const float* __restrict__ bias, float* __restrict__ out) {
  __shared__ __align__(16) unsigned short smem[16384];  // 32 KB
  const int tid = threadIdx.x;
  const int w = blockIdx.x;
  const int t = (w & 7) * 294 + (w >> 3);   // 2352 = 8 x 294; 294 = 98x3
  const int bm = t / 3, bn = t - bm * 3;
  const int lane = tid & 63, wv = tid >> 6;
  const int wm = wv >> 1, wn = wv & 1;
  const int lo = lane & 15, hi = lane >> 4;

  const int sr0 = tid >> 2, sq0 = (tid & 3) ^ ((sr0 >> 1) & 3);
  const int ci1 = tid + 256;
  const int sr1 = ci1 >> 2, sq1 = (ci1 & 3) ^ ((sr1 >> 1) & 3);

  const unsigned short* Ab = A + (size_t)bm * 128 * 384;
  const unsigned short* Wb = W + (size_t)bn * 128 * 384;

  f32x4 acc[4][4];
#pragma unroll
  for (int i = 0; i < 4; i++)
#pragma unroll
    for (int j = 0; j < 4; j++)
#pragma unroll
      for (int r = 0; r < 4; r++) acc[i][j][r] = 0.0f;

  {
    unsigned short* b0 = smem;
    GL16(Ab + sr0 * 384 + sq0 * 8, b0 + tid * 8);
    GL16(Ab + sr1 * 384 + sq1 * 8, b0 + ci1 * 8);
    GL16(Wb + sr0 * 384 + sq0 * 8, b0 + 4096 + tid * 8);
    GL16(Wb + sr1 * 384 + sq1 * 8, b0 + 4096 + ci1 * 8);
  }
  __syncthreads();

  int buf = 0;
  for (int kt = 0; kt < 12; kt++) {
    if (kt < 11) {
      const int kk = (kt + 1) * 32;
      unsigned short* nb = smem + (buf ^ 1) * 8192;
      GL16(Ab + sr0 * 384 + kk + sq0 * 8, nb + tid * 8);
      GL16(Ab + sr1 * 384 + kk + sq1 * 8, nb + ci1 * 8);
      GL16(Wb + sr0 * 384 + kk + sq0 * 8, nb + 4096 + tid * 8);
      GL16(Wb + sr1 * 384 + kk + sq1 * 8, nb + 4096 + ci1 * 8);
    }
    const unsigned short* ba = smem + buf * 8192;
    bf16x8 af[4], bfm[4];
#pragma unroll
    for (int mt = 0; mt < 4; mt++) {
      const int row = wm * 64 + mt * 16 + lo;
      af[mt] = *(const bf16x8*)&ba[(row * 4 + (hi ^ ((row >> 1) & 3))) * 8];
    }
#pragma unroll
    for (int nt = 0; nt < 4; nt++) {
      const int row = wn * 64 + nt * 16 + lo;
      bfm[nt] = *(const bf16x8*)&ba[4096 + (row * 4 + (hi ^ ((row >> 1) & 3))) * 8];
    }
#pragma unroll
    for (int mt = 0; mt < 4; mt++)
#pragma unroll
      for (int nt = 0; nt < 4; nt++)
        acc[mt][nt] = __builtin_amdgcn_mfma_f32_16x16x32_bf16(af[mt], bfm[nt], acc[mt][nt], 0, 0, 0);
    __syncthreads();
    buf ^= 1;
  }

#pragma unroll
  for (int nt = 0; nt < 4; nt++) {
    const int j = bn * 128 + wn * 64 + nt * 16 + lo;
    const float bj = bias[j];
#pragma unroll
    for (int mt = 0; mt < 4; mt++) {
#pragma unroll
      for (int r = 0; r < 4; r++) {
        const int i = bm * 128 + wm * 64 + mt * 16 + hi * 4 + r;
        out[(size_t)i * 384 + j] = acc[mt][nt][r] + bj;
      }
    }
  }
}

// ---------------------------------------------------------------------------
extern "C" void kernel_launch(void* const* d_in, const int* in_sizes, int n_in,
                              void* d_out, int out_size, void* d_ws, size_t ws_size,
                              hipStream_t stream) {
  const float* x      = (const float*)d_in[0];
  const float* mask   = (const float*)d_in[1];
  const float* qkv_w  = (const float*)d_in[2];
  const float* qkv_b  = (const float*)d_in[3];
  const float* proj_w = (const float*)d_in[4];
  const float* proj_b = (const float*)d_in[5];
  const float* rpb    = (const float*)d_in[6];
  const int*   ridx   = (const int*)d_in[7];

  // ws: qkv 231.2 MB | x_bf/av (aliased) 77.1 MB | comb 12.6 MB | weights
  unsigned short* qkv   = (unsigned short*)d_ws;
  unsigned short* x_bf  = qkv + (size_t)3 * BH * N_ * D_;   // alias: av
  unsigned short* av    = x_bf;
  float* comb           = (float*)(x_bf + (size_t)M_ROWS * C_);
  unsigned short* wq_bf = (unsigned short*)(comb + 768 * 4096);
  unsigned short* wp_bf = wq_bf + 1152 * 384;
  float* out   = (float*)d_out;
  float* probs = out + (size_t)M_ROWS * C_;

  prep<<<3104, 256, 0, stream>>>(x, qkv_w, proj_w, mask, rpb, ridx,
                                 x_bf, wq_bf, wp_bf, comb);
  qkv_gemm<<<7056, 256, 0, stream>>>(x_bf, wq_bf, qkv_b, qkv);
  attn_kernel<<<dim3(H_, B_TOT), 64, 0, stream>>>(qkv, comb, probs, av);
  proj_gemm<<<2352, 256, 0, stream>>>(av, wp_bf, proj_b, out);
}